// Round 1
// baseline (1424.387 us; speedup 1.0000x reference)
//
#include <hip/hip_runtime.h>

#define B_  256
#define M_  80
#define T_  1000
#define H_  128
#define G3  384   // 3*H

__device__ __forceinline__ float sigmoid_f(float v) {
    return 1.0f / (1.0f + __expf(-v));
}
__device__ __forceinline__ float tanh_f(float v) {
    // tanh(v) = 1 - 2/(1+exp(2v)); stable at +/-inf
    return 1.0f - 2.0f / (1.0f + __expf(2.0f * v));
}

// One block per batch element. 768 threads = 12 waves (3/SIMD).
// Thread i handles gate-row g=i>>1, k-half kh=i&1.
// Weights held in VGPRs; h and x_t broadcast from LDS.
__global__ __launch_bounds__(768) void gru_kernel(
    const float* __restrict__ x,      // (B, M, T)
    const float* __restrict__ W_ih,   // (3H, M)
    const float* __restrict__ W_hh,   // (3H, H)
    const float* __restrict__ b_ih,   // (3H,)
    const float* __restrict__ b_hh,   // (3H,)
    float* __restrict__ out)          // (B, H)
{
    const int b   = blockIdx.x;
    const int tid = threadIdx.x;
    const int g   = tid >> 1;   // 0..383
    const int kh  = tid & 1;    // k-half: 0 -> first half, 1 -> second half

    __shared__ float h_lds[H_];
    __shared__ float A[G3];       // gx_t + b_ih
    __shared__ float Hh[G3];      // gh_t + b_hh
    __shared__ float xs[2][M_];   // double-buffered x column

    // ---- preload weights into registers (one-time; L2-served after first block) ----
    float wih[40];
#pragma unroll
    for (int j = 0; j < 40; ++j) wih[j] = W_ih[g * M_ + kh * 40 + j];
    float whh[64];
#pragma unroll
    for (int j = 0; j < 64; ++j) whh[j] = W_hh[g * H_ + kh * 64 + j];
    const float bia = kh ? 0.0f : b_ih[g];
    const float bha = kh ? 0.0f : b_hh[g];

    const float* xb = x + (size_t)b * M_ * T_;

    float h_r = 0.0f;                       // master h (threads 0..127)
    if (tid < H_) h_lds[tid] = 0.0f;
    if (tid >= 512 && tid < 512 + M_) {     // stage x column t=0
        xs[0][tid - 512] = xb[(size_t)(tid - 512) * T_];
    }

    for (int t = 0; t < T_; ++t) {
        __syncthreads();                    // h_lds (h_{t-1}) and xs[cb] (x_t) ready
        const int cb = t & 1, nb = cb ^ 1;

        // prefetch x column t+1 (latency hidden under the GEMV below)
        float xv = 0.0f;
        const int m  = tid - 512;
        const int tn = (t + 1 < T_) ? (t + 1) : (T_ - 1);
        if (tid >= 512 && tid < 512 + M_) xv = xb[(size_t)m * T_ + tn];

        // ---- GEMV halves: a = W_ih[g,:] . x_t ; h = W_hh[g,:] . h_{t-1} ----
        float aa = bia, ah = bha;
        const float4* xv4 = (const float4*)(&xs[cb][kh * 40]);
#pragma unroll
        for (int q = 0; q < 10; ++q) {
            float4 xq = xv4[q];
            aa = fmaf(xq.x, wih[4 * q + 0], aa);
            aa = fmaf(xq.y, wih[4 * q + 1], aa);
            aa = fmaf(xq.z, wih[4 * q + 2], aa);
            aa = fmaf(xq.w, wih[4 * q + 3], aa);
        }
        const float4* hv4 = (const float4*)(&h_lds[kh * 64]);
#pragma unroll
        for (int q = 0; q < 16; ++q) {
            float4 hq = hv4[q];
            ah = fmaf(hq.x, whh[4 * q + 0], ah);
            ah = fmaf(hq.y, whh[4 * q + 1], ah);
            ah = fmaf(hq.z, whh[4 * q + 2], ah);
            ah = fmaf(hq.w, whh[4 * q + 3], ah);
        }
        // combine the two k-halves (lanes tid, tid^1 are in the same wave)
        aa += __shfl_xor(aa, 1);
        ah += __shfl_xor(ah, 1);
        if (!kh) { A[g] = aa; Hh[g] = ah; }

        // publish prefetched x column into the other buffer
        if (tid >= 512 && tid < 512 + M_) xs[nb][m] = xv;

        __syncthreads();                    // A / Hh ready

        // ---- gates + state update (threads 0..127, one hidden unit each) ----
        if (tid < H_) {
            const float r  = sigmoid_f(A[tid] + Hh[tid]);
            const float z  = sigmoid_f(A[tid + H_] + Hh[tid + H_]);
            const float nv = tanh_f(fmaf(r, Hh[tid + 2 * H_], A[tid + 2 * H_]));
            h_r = (1.0f - z) * nv + z * h_r;
            h_lds[tid] = h_r;               // visible to GEMV after next top barrier
        }
    }

    if (tid < H_) out[(size_t)b * H_ + tid] = h_r;
}

extern "C" void kernel_launch(void* const* d_in, const int* in_sizes, int n_in,
                              void* d_out, int out_size, void* d_ws, size_t ws_size,
                              hipStream_t stream) {
    const float* x    = (const float*)d_in[0];
    const float* W_ih = (const float*)d_in[1];
    const float* W_hh = (const float*)d_in[2];
    const float* b_ih = (const float*)d_in[3];
    const float* b_hh = (const float*)d_in[4];
    float* out = (float*)d_out;

    gru_kernel<<<dim3(B_), dim3(768), 0, stream>>>(x, W_ih, W_hh, b_ih, b_hh, out);
}

// Round 2
// 1136.143 us; speedup vs baseline: 1.2537x; 1.2537x over previous
//
#include <hip/hip_runtime.h>

#define B_  256
#define M_  80
#define T_  1000
#define H_  128
#define G3  384   // 3*H
#define HP  68    // padded half-stride for h_lds: 64 + 4 floats so the two
                  // per-wave broadcast addresses hit disjoint bank groups

__device__ __forceinline__ float sigmoid_f(float v) {
    return 1.0f / (1.0f + __expf(-v));
}
__device__ __forceinline__ float tanh_f(float v) {
    return 1.0f - 2.0f / (1.0f + __expf(2.0f * v));  // stable at +/-inf
}

// One block per batch element (grid 256 = CU count). 768 threads = 12 waves
// (3/SIMD). Thread i: gate-row g=i>>1, k-half kh=i&1. Weights pinned in VGPRs
// (launch_bounds(768,3) -> VGPR cap ~168; asm fence defeats load-sinking).
__global__ __launch_bounds__(768, 3) void gru_kernel(
    const float* __restrict__ x,      // (B, M, T)
    const float* __restrict__ W_ih,   // (3H, M)
    const float* __restrict__ W_hh,   // (3H, H)
    const float* __restrict__ b_ih,   // (3H,)
    const float* __restrict__ b_hh,   // (3H,)
    float* __restrict__ out)          // (B, H)
{
    const int b   = blockIdx.x;
    const int tid = threadIdx.x;
    const int g   = tid >> 1;   // 0..383
    const int kh  = tid & 1;    // k-half

    __shared__ __align__(16) float h_lds[2 * HP];
    __shared__ __align__(16) float A[G3];       // gx_t + b_ih
    __shared__ __align__(16) float Hh[G3];      // gh_t + b_hh
    __shared__ __align__(16) float xs[2][M_];   // double-buffered x column

    // ---- one-time weight preload into VGPRs ----
    float wih[40];
#pragma unroll
    for (int j = 0; j < 40; ++j) wih[j] = W_ih[g * M_ + kh * 40 + j];
    float whh[64];
#pragma unroll
    for (int j = 0; j < 64; ++j) whh[j] = W_hh[g * H_ + kh * 64 + j];
    // Pin: make re-loading inside the loop illegal (values "modified" here).
#pragma unroll
    for (int j = 0; j < 40; ++j) asm volatile("" : "+v"(wih[j]));
#pragma unroll
    for (int j = 0; j < 64; ++j) asm volatile("" : "+v"(whh[j]));

    const float bia = kh ? 0.0f : b_ih[g];
    const float bha = kh ? 0.0f : b_hh[g];

    const float* xb = x + (size_t)b * M_ * T_;

    float h_r = 0.0f;                       // master h (threads 0..127)
    if (tid < 2 * HP) h_lds[tid] = 0.0f;
    if (tid >= 512 && tid < 512 + M_) {     // stage x column t=0
        xs[0][tid - 512] = xb[(size_t)(tid - 512) * T_];
    }

    for (int t = 0; t < T_; ++t) {
        __syncthreads();                    // h_lds (h_{t-1}) and xs[cb] (x_t) ready
        const int cb = t & 1, nb = cb ^ 1;

        // prefetch x column t+1 (latency hidden under the GEMV)
        float xv = 0.0f;
        const int m  = tid - 512;
        const int tn = (t + 1 < T_) ? (t + 1) : (T_ - 1);
        if (tid >= 512 && tid < 512 + M_) xv = xb[(size_t)m * T_ + tn];

        // ---- GEMV halves ----
        float aa = bia, ah = bha;
        const float4* xv4 = (const float4*)(&xs[cb][kh * 40]);
#pragma unroll
        for (int q = 0; q < 10; ++q) {
            float4 xq = xv4[q];
            aa = fmaf(xq.x, wih[4 * q + 0], aa);
            aa = fmaf(xq.y, wih[4 * q + 1], aa);
            aa = fmaf(xq.z, wih[4 * q + 2], aa);
            aa = fmaf(xq.w, wih[4 * q + 3], aa);
        }
        const float4* hv4 = (const float4*)(&h_lds[kh * HP]);
#pragma unroll
        for (int q = 0; q < 16; ++q) {
            float4 hq = hv4[q];
            ah = fmaf(hq.x, whh[4 * q + 0], ah);
            ah = fmaf(hq.y, whh[4 * q + 1], ah);
            ah = fmaf(hq.z, whh[4 * q + 2], ah);
            ah = fmaf(hq.w, whh[4 * q + 3], ah);
        }
        // combine k-halves (lanes tid, tid^1 share a wave)
        aa += __shfl_xor(aa, 1);
        ah += __shfl_xor(ah, 1);
        if (!kh) { A[g] = aa; Hh[g] = ah; }

        if (tid >= 512 && tid < 512 + M_) xs[nb][m] = xv;

        __syncthreads();                    // A / Hh ready

        // ---- gates + state update (threads 0..127) ----
        if (tid < H_) {
            const float r  = sigmoid_f(A[tid] + Hh[tid]);
            const float z  = sigmoid_f(A[tid + H_] + Hh[tid + H_]);
            const float nv = tanh_f(fmaf(r, Hh[tid + 2 * H_], A[tid + 2 * H_]));
            h_r = (1.0f - z) * nv + z * h_r;
            h_lds[(tid < 64) ? tid : tid + 4] = h_r;   // padded layout
        }
    }

    if (tid < H_) out[(size_t)b * H_ + tid] = h_r;
}

extern "C" void kernel_launch(void* const* d_in, const int* in_sizes, int n_in,
                              void* d_out, int out_size, void* d_ws, size_t ws_size,
                              hipStream_t stream) {
    const float* x    = (const float*)d_in[0];
    const float* W_ih = (const float*)d_in[1];
    const float* W_hh = (const float*)d_in[2];
    const float* b_ih = (const float*)d_in[3];
    const float* b_hh = (const float*)d_in[4];
    float* out = (float*)d_out;

    gru_kernel<<<dim3(B_), dim3(768), 0, stream>>>(x, W_ih, W_hh, b_ih, b_hh, out);
}

// Round 3
// 844.481 us; speedup vs baseline: 1.6867x; 1.3454x over previous
//
#include <hip/hip_runtime.h>
#include <stdint.h>

#define B_  256
#define M_  80
#define T_  1000
#define H_  128

typedef _Float16 half2_t __attribute__((ext_vector_type(2)));

__device__ __forceinline__ float sigmoid_f(float v) { return 1.0f / (1.0f + __expf(-v)); }
__device__ __forceinline__ float tanh_f(float v)    { return 1.0f - 2.0f / (1.0f + __expf(2.0f * v)); }

// add across each aligned quad of lanes (c = lane&3) via DPP quad_perm (pure VALU)
__device__ __forceinline__ float qreduce(float v) {
    int t = __builtin_amdgcn_update_dpp(0, __builtin_bit_cast(int, v), 0xB1, 0xF, 0xF, true); // [1,0,3,2]
    v += __builtin_bit_cast(float, t);
    t = __builtin_amdgcn_update_dpp(0, __builtin_bit_cast(int, v), 0x4E, 0xF, 0xF, true);     // [2,3,0,1]
    v += __builtin_bit_cast(float, t);
    return v;
}

__device__ __forceinline__ float dot2f(uint32_t w, uint32_t o, float acc) {
#if __has_builtin(__builtin_amdgcn_fdot2)
    return __builtin_amdgcn_fdot2(__builtin_bit_cast(half2_t, w),
                                  __builtin_bit_cast(half2_t, o), acc, false);
#else
    half2_t wv = __builtin_bit_cast(half2_t, w), ov = __builtin_bit_cast(half2_t, o);
    return fmaf((float)wv.x, (float)ov.x, fmaf((float)wv.y, (float)ov.y, acc));
#endif
}

// 512 threads = 8 waves (2/SIMD, balanced). Thread: c = tid&3 (col-chunk),
// rg = tid>>2 (row-group -> rows rg, rg+128, rg+256 = one r/z/n row sharing
// ONE operand fragment: 20 x-cols + 32 h-cols). Weights: f16-packed, 84 VGPRs.
__global__ __launch_bounds__(512, 2) void gru_kernel(
    const float* __restrict__ x,      // (B, M, T)
    const float* __restrict__ W_ih,   // (3H, M)
    const float* __restrict__ W_hh,   // (3H, H)
    const float* __restrict__ b_ih,   // (3H,)
    const float* __restrict__ b_hh,   // (3H,)
    float* __restrict__ out)          // (B, H)
{
    const int b   = blockIdx.x;
    const int tid = threadIdx.x;
    const int c   = tid & 3;
    const int rg  = tid >> 2;

    __shared__ __align__(16) _Float16 xs16[2][4][24];  // x col, f16, chunk-padded to 24
    __shared__ __align__(16) _Float16 h16[H_];         // h_{t-1}, f16
    __shared__ __align__(16) float Rg[H_], Zg[H_], An[H_], Hn[H_];

    // ---- one-time: pack weights to f16 pairs in VGPRs ----
    uint32_t wx[3][12];   // x-side: 24 elements/row (last 4 zero-padded)
    uint32_t wh[3][16];   // h-side: 32 elements/row
#pragma unroll
    for (int rr = 0; rr < 3; ++rr) {
        const int row = rg + rr * 128;
        const float* wp = W_ih + row * M_ + 20 * c;
        float tmp[24];
#pragma unroll
        for (int j = 0; j < 20; ++j) tmp[j] = wp[j];
#pragma unroll
        for (int j = 20; j < 24; ++j) tmp[j] = 0.0f;
#pragma unroll
        for (int j = 0; j < 12; ++j) {
            half2_t p; p.x = (_Float16)tmp[2 * j]; p.y = (_Float16)tmp[2 * j + 1];
            wx[rr][j] = __builtin_bit_cast(uint32_t, p);
        }
        const float* hp = W_hh + row * H_ + 32 * c;
#pragma unroll
        for (int j = 0; j < 16; ++j) {
            half2_t p; p.x = (_Float16)hp[2 * j]; p.y = (_Float16)hp[2 * j + 1];
            wh[rr][j] = __builtin_bit_cast(uint32_t, p);
        }
    }
#pragma unroll
    for (int rr = 0; rr < 3; ++rr) {
#pragma unroll
        for (int j = 0; j < 12; ++j) asm volatile("" : "+v"(wx[rr][j]));
#pragma unroll
        for (int j = 0; j < 16; ++j) asm volatile("" : "+v"(wh[rr][j]));
    }

    // biases: added once per step by lane c==0 only (pre-reduction)
    float bR = 0.f, bZ = 0.f, bAn = 0.f, bHn = 0.f;
    if (c == 0) {
        bR  = b_ih[rg] + b_hh[rg];
        bZ  = b_ih[rg + 128] + b_hh[rg + 128];
        bAn = b_ih[rg + 256];
        bHn = b_hh[rg + 256];
    }
    asm volatile("" : "+v"(bR), "+v"(bZ), "+v"(bAn), "+v"(bHn));

    const float* xb = x + (size_t)b * M_ * T_;
    const int pc = tid / 20, pi = tid % 20;   // prefetch slot (tid < 80)

    // ---- init LDS: zero xs (incl. pads), zero h ----
    if (tid < 2 * 4 * 24) ((short*)xs16)[tid] = 0;
    __syncthreads();
    if (tid < M_) xs16[0][pc][pi] = (_Float16)xb[(size_t)tid * T_];  // x col t=0
    if (tid < H_) h16[tid] = (_Float16)0.0f;

    float h_r = 0.0f;   // master h, fp32 (threads 0..127)

    for (int t = 0; t < T_; ++t) {
        __syncthreads();                 // h16 (h_{t-1}) and xs16[cb] (x_t) ready
        const int cb = t & 1, nb = cb ^ 1;

        // prefetch x column t+1 (global, latency hidden under GEMV)
        float xv = 0.0f;
        const int tn = (t + 1 < T_) ? (t + 1) : (T_ - 1);
        if (tid < M_) xv = xb[(size_t)tid * T_ + tn];

        // ---- operand fragment (shared by this thread's 3 rows) ----
        const uint4* xp = (const uint4*)(&xs16[cb][c][0]);
        uint4 xA = xp[0], xB = xp[1], xC = xp[2];
        uint32_t ox[12] = { xA.x, xA.y, xA.z, xA.w, xB.x, xB.y, xB.z, xB.w,
                            xC.x, xC.y, xC.z, xC.w };
        const uint4* hq = (const uint4*)(&h16[32 * c]);
        uint4 hA = hq[0], hB = hq[1], hC = hq[2], hD = hq[3];
        uint32_t oh[16] = { hA.x, hA.y, hA.z, hA.w, hB.x, hB.y, hB.z, hB.w,
                            hC.x, hC.y, hC.z, hC.w, hD.x, hD.y, hD.z, hD.w };

        // ---- 3 rows x 52 cols, fp32 accum via v_dot2_f32_f16 ----
        float a_r = bR, a_z = bZ, a_n = bAn, h_n = bHn;
#pragma unroll
        for (int j = 0; j < 12; ++j) a_r = dot2f(wx[0][j], ox[j], a_r);
#pragma unroll
        for (int j = 0; j < 16; ++j) a_r = dot2f(wh[0][j], oh[j], a_r);
#pragma unroll
        for (int j = 0; j < 12; ++j) a_z = dot2f(wx[1][j], ox[j], a_z);
#pragma unroll
        for (int j = 0; j < 16; ++j) a_z = dot2f(wh[1][j], oh[j], a_z);
#pragma unroll
        for (int j = 0; j < 12; ++j) a_n = dot2f(wx[2][j], ox[j], a_n);
#pragma unroll
        for (int j = 0; j < 16; ++j) h_n = dot2f(wh[2][j], oh[j], h_n);

        a_r = qreduce(a_r); a_z = qreduce(a_z);
        a_n = qreduce(a_n); h_n = qreduce(h_n);
        if (c == 0) { Rg[rg] = a_r; Zg[rg] = a_z; An[rg] = a_n; Hn[rg] = h_n; }

        // publish prefetched x column into the other buffer
        if (tid < M_) xs16[nb][pc][pi] = (_Float16)xv;

        __syncthreads();                 // Rg/Zg/An/Hn ready

        // ---- gates + state update (threads 0..127) ----
        if (tid < H_) {
            const float r  = sigmoid_f(Rg[tid]);
            const float z  = sigmoid_f(Zg[tid]);
            const float nv = tanh_f(fmaf(r, Hn[tid], An[tid]));
            h_r = (1.0f - z) * nv + z * h_r;
            h16[tid] = (_Float16)h_r;    // visible after next top barrier
        }
    }

    if (tid < H_) out[(size_t)b * H_ + tid] = h_r;
}

extern "C" void kernel_launch(void* const* d_in, const int* in_sizes, int n_in,
                              void* d_out, int out_size, void* d_ws, size_t ws_size,
                              hipStream_t stream) {
    const float* x    = (const float*)d_in[0];
    const float* W_ih = (const float*)d_in[1];
    const float* W_hh = (const float*)d_in[2];
    const float* b_ih = (const float*)d_in[3];
    const float* b_hh = (const float*)d_in[4];
    float* out = (float*)d_out;

    gru_kernel<<<dim3(B_), dim3(512), 0, stream>>>(x, W_ih, W_hh, b_ih, b_hh, out);
}

// Round 5
// 827.059 us; speedup vs baseline: 1.7222x; 1.0211x over previous
//
#include <hip/hip_runtime.h>
#include <stdint.h>

#define B_  256
#define M_  80
#define T_  1000
#define H_  128

typedef _Float16 half2_t __attribute__((ext_vector_type(2)));

__device__ __forceinline__ float sigmoid_f(float v) { return 1.0f / (1.0f + __expf(-v)); }
__device__ __forceinline__ float tanh_f(float v)    { return 1.0f - 2.0f / (1.0f + __expf(2.0f * v)); }

// butterfly sum across each aligned quad (all 4 lanes end with the total)
__device__ __forceinline__ float qsum(float v) {
    int t = __builtin_amdgcn_update_dpp(0, __builtin_bit_cast(int, v), 0xB1, 0xF, 0xF, true); // [1,0,3,2]
    v += __builtin_bit_cast(float, t);
    t = __builtin_amdgcn_update_dpp(0, __builtin_bit_cast(int, v), 0x4E, 0xF, 0xF, true);     // [2,3,0,1]
    v += __builtin_bit_cast(float, t);
    return v;
}

__device__ __forceinline__ float dot2f(uint32_t w, uint32_t o, float acc) {
#if __has_builtin(__builtin_amdgcn_fdot2)
    return __builtin_amdgcn_fdot2(__builtin_bit_cast(half2_t, w),
                                  __builtin_bit_cast(half2_t, o), acc, false);
#else
    half2_t wv = __builtin_bit_cast(half2_t, w), ov = __builtin_bit_cast(half2_t, o);
    return fmaf((float)wv.x, (float)ov.x, fmaf((float)wv.y, (float)ov.y, acc));
#endif
}

// 512 threads = 8 waves (2/SIMD). Thread: c = tid&3 (col-chunk), rg = tid>>2
// (hidden unit; rows rg, rg+128, rg+256 share one operand fragment).
// ONE barrier per step; h16 is DOUBLE-BUFFERED (read cb, write nb) so the
// bottom-of-step h write cannot race a slow wave's top-of-step h read (the
// R4 failure). Quad butterfly gives all 4 lanes all 4 gate sums -> gates
// computed inline, redundantly per quad; master h lives in registers.
__global__ __launch_bounds__(512, 2) void gru_kernel(
    const float* __restrict__ x,      // (B, M, T)
    const float* __restrict__ W_ih,   // (3H, M)
    const float* __restrict__ W_hh,   // (3H, H)
    const float* __restrict__ b_ih,   // (3H,)
    const float* __restrict__ b_hh,   // (3H,)
    float* __restrict__ out)          // (B, H)
{
    const int b   = blockIdx.x;
    const int tid = threadIdx.x;
    const int c   = tid & 3;
    const int rg  = tid >> 2;

    __shared__ __align__(16) _Float16 xs16[2][4][24];  // x col, f16, chunk-padded to 24
    __shared__ __align__(16) _Float16 h16[2][H_];      // h, f16, DOUBLE-BUFFERED

    // ---- one-time: pack weights to f16 pairs in VGPRs ----
    uint32_t wx[3][12];   // x-side: 20 cols/chunk, padded to 24
    uint32_t wh[3][16];   // h-side: 32 cols/chunk
#pragma unroll
    for (int rr = 0; rr < 3; ++rr) {
        const int row = rg + rr * 128;
        const float* wp = W_ih + row * M_ + 20 * c;
        float tmp[24];
#pragma unroll
        for (int j = 0; j < 20; ++j) tmp[j] = wp[j];
#pragma unroll
        for (int j = 20; j < 24; ++j) tmp[j] = 0.0f;
#pragma unroll
        for (int j = 0; j < 12; ++j) {
            half2_t p; p.x = (_Float16)tmp[2 * j]; p.y = (_Float16)tmp[2 * j + 1];
            wx[rr][j] = __builtin_bit_cast(uint32_t, p);
        }
        const float* hp = W_hh + row * H_ + 32 * c;
#pragma unroll
        for (int j = 0; j < 16; ++j) {
            half2_t p; p.x = (_Float16)hp[2 * j]; p.y = (_Float16)hp[2 * j + 1];
            wh[rr][j] = __builtin_bit_cast(uint32_t, p);
        }
    }
#pragma unroll
    for (int rr = 0; rr < 3; ++rr) {
#pragma unroll
        for (int j = 0; j < 12; ++j) asm volatile("" : "+v"(wx[rr][j]));
#pragma unroll
        for (int j = 0; j < 16; ++j) asm volatile("" : "+v"(wh[rr][j]));
    }

    // biases on lane c==0 only (summed once by the butterfly)
    float bR = 0.f, bZ = 0.f, bAn = 0.f, bHn = 0.f;
    if (c == 0) {
        bR  = b_ih[rg] + b_hh[rg];
        bZ  = b_ih[rg + 128] + b_hh[rg + 128];
        bAn = b_ih[rg + 256];
        bHn = b_hh[rg + 256];
    }
    asm volatile("" : "+v"(bR), "+v"(bZ), "+v"(bAn), "+v"(bHn));

    const float* xb = x + (size_t)b * M_ * T_;
    const int pc = tid / 20, pi = tid % 20;   // prefetch slot (tid < 80)

    if (tid < 2 * 4 * 24) ((short*)xs16)[tid] = 0;   // zero pads
    __syncthreads();
    if (tid < M_) xs16[0][pc][pi] = (_Float16)xb[(size_t)tid * T_];  // x col t=0
    if (tid < H_) h16[0][tid] = (_Float16)0.0f;      // h_{-1} read at t=0 (cb=0)

    float h_r = 0.0f;   // master h (consistent across the quad)

    for (int t = 0; t < T_; ++t) {
        __syncthreads();                 // h16[cb] (h_{t-1}) and xs16[cb] (x_t) ready
        const int cb = t & 1, nb = cb ^ 1;

        // prefetch x column t+1 (global; completes under the dot2 block)
        float xv = 0.0f;
        const int tn = (t + 1 < T_) ? (t + 1) : (T_ - 1);
        if (tid < M_) xv = xb[(size_t)tid * T_ + tn];

        // operand fragment (shared by this thread's 3 rows)
        const uint4* xp = (const uint4*)(&xs16[cb][c][0]);
        uint4 xA = xp[0], xB = xp[1], xC = xp[2];
        uint32_t ox[12] = { xA.x, xA.y, xA.z, xA.w, xB.x, xB.y, xB.z, xB.w,
                            xC.x, xC.y, xC.z, xC.w };
        const uint4* hq = (const uint4*)(&h16[cb][32 * c]);
        uint4 hA = hq[0], hB = hq[1], hC = hq[2], hD = hq[3];
        uint32_t oh[16] = { hA.x, hA.y, hA.z, hA.w, hB.x, hB.y, hB.z, hB.w,
                            hC.x, hC.y, hC.z, hC.w, hD.x, hD.y, hD.z, hD.w };

        // 3 rows x 52 cols, fp32 accum via v_dot2_f32_f16 (4 independent chains)
        float a_r = bR, a_z = bZ, a_n = bAn, h_n = bHn;
#pragma unroll
        for (int j = 0; j < 12; ++j) a_r = dot2f(wx[0][j], ox[j], a_r);
#pragma unroll
        for (int j = 0; j < 16; ++j) a_r = dot2f(wh[0][j], oh[j], a_r);
#pragma unroll
        for (int j = 0; j < 12; ++j) a_z = dot2f(wx[1][j], ox[j], a_z);
#pragma unroll
        for (int j = 0; j < 16; ++j) a_z = dot2f(wh[1][j], oh[j], a_z);
#pragma unroll
        for (int j = 0; j < 12; ++j) a_n = dot2f(wx[2][j], ox[j], a_n);
#pragma unroll
        for (int j = 0; j < 16; ++j) h_n = dot2f(wh[2][j], oh[j], h_n);

        a_r = qsum(a_r); a_z = qsum(a_z);
        a_n = qsum(a_n); h_n = qsum(h_n);

        // publish prefetched x column into the other buffer (disjoint from reads)
        if (tid < M_) xs16[nb][pc][pi] = (_Float16)xv;

        // ---- gates inline (all 4 lanes of the quad, redundantly) ----
        const float r  = sigmoid_f(a_r);
        const float z  = sigmoid_f(a_z);
        const float nv = tanh_f(fmaf(r, h_n, a_n));
        h_r = (1.0f - z) * nv + z * h_r;
        if (c == 0) h16[nb][rg] = (_Float16)h_r;   // write OTHER buffer: no WAR race
    }

    if (c == 0) out[(size_t)b * H_ + rg] = h_r;
}

extern "C" void kernel_launch(void* const* d_in, const int* in_sizes, int n_in,
                              void* d_out, int out_size, void* d_ws, size_t ws_size,
                              hipStream_t stream) {
    const float* x    = (const float*)d_in[0];
    const float* W_ih = (const float*)d_in[1];
    const float* W_hh = (const float*)d_in[2];
    const float* b_ih = (const float*)d_in[3];
    const float* b_hh = (const float*)d_in[4];
    float* out = (float*)d_out;

    gru_kernel<<<dim3(B_), dim3(512), 0, stream>>>(x, W_ih, W_hh, b_ih, b_hh, out);
}

// Round 6
// 745.958 us; speedup vs baseline: 1.9095x; 1.1087x over previous
//
#include <hip/hip_runtime.h>
#include <stdint.h>

#define B_  256
#define M_  80
#define T_  1000
#define H_  128

typedef _Float16 half2_t __attribute__((ext_vector_type(2)));

#define LOG2E 1.44269504f

// guaranteed single-instruction packed dot: acc += w.x*o.x + w.y*o.y (f16 in, f32 acc)
__device__ __forceinline__ float dot2f(uint32_t w, uint32_t o, float acc) {
    asm volatile("v_dot2_f32_f16 %0, %1, %2, %0" : "+v"(acc) : "v"(w), "v"(o));
    return acc;
}

// butterfly sum across each aligned quad (all 4 lanes end with the total)
__device__ __forceinline__ float qsum(float v) {
    int t = __builtin_amdgcn_update_dpp(0, __builtin_bit_cast(int, v), 0xB1, 0xF, 0xF, true); // [1,0,3,2]
    v += __builtin_bit_cast(float, t);
    t = __builtin_amdgcn_update_dpp(0, __builtin_bit_cast(int, v), 0x4E, 0xF, 0xF, true);     // [2,3,0,1]
    v += __builtin_bit_cast(float, t);
    return v;
}

__device__ __forceinline__ float fast_sigmoid(float v) {
    // 1/(1+2^(-v*log2e)) : mul, exp, add, rcp — no div sequence
    return __builtin_amdgcn_rcpf(1.0f + __builtin_amdgcn_exp2f(-LOG2E * v));
}
__device__ __forceinline__ float fast_tanh(float v) {
    // 1 - 2/(1+2^(2v*log2e))
    return fmaf(-2.0f, __builtin_amdgcn_rcpf(1.0f + __builtin_amdgcn_exp2f(2.0f * LOG2E * v)), 1.0f);
}

// 512 threads = 8 waves (2/SIMD). Thread: c = tid&3 (col-chunk), rg = tid>>2
// (hidden unit; rows rg, rg+128, rg+256 share one operand fragment).
// ONE barrier per step; h16 double-buffered (read cb, write nb). Quad
// butterfly gives all lanes all 4 gate sums -> gates inline per quad.
__global__ __launch_bounds__(512, 2) void gru_kernel(
    const float* __restrict__ x,      // (B, M, T)
    const float* __restrict__ W_ih,   // (3H, M)
    const float* __restrict__ W_hh,   // (3H, H)
    const float* __restrict__ b_ih,   // (3H,)
    const float* __restrict__ b_hh,   // (3H,)
    float* __restrict__ out)          // (B, H)
{
    const int b   = blockIdx.x;
    const int tid = threadIdx.x;
    const int c   = tid & 3;
    const int rg  = tid >> 2;

    __shared__ __align__(16) _Float16 xs16[2][4][24];  // x col, f16, chunk-padded to 24
    __shared__ __align__(16) _Float16 h16[2][H_];      // h, f16, double-buffered

    // ---- one-time: pack weights to f16 pairs ----
    uint32_t wx[3][12];   // x-side: 20 cols/chunk, padded to 24
    uint32_t wh[3][16];   // h-side: 32 cols/chunk
#pragma unroll
    for (int rr = 0; rr < 3; ++rr) {
        const int row = rg + rr * 128;
        const float* wp = W_ih + row * M_ + 20 * c;
        float tmp[24];
#pragma unroll
        for (int j = 0; j < 20; ++j) tmp[j] = wp[j];
#pragma unroll
        for (int j = 20; j < 24; ++j) tmp[j] = 0.0f;
#pragma unroll
        for (int j = 0; j < 12; ++j) {
            half2_t p; p.x = (_Float16)tmp[2 * j]; p.y = (_Float16)tmp[2 * j + 1];
            wx[rr][j] = __builtin_bit_cast(uint32_t, p);
        }
        const float* hp = W_hh + row * H_ + 32 * c;
#pragma unroll
        for (int j = 0; j < 16; ++j) {
            half2_t p; p.x = (_Float16)hp[2 * j]; p.y = (_Float16)hp[2 * j + 1];
            wh[rr][j] = __builtin_bit_cast(uint32_t, p);
        }
    }
#pragma unroll
    for (int rr = 0; rr < 3; ++rr) {
#pragma unroll
        for (int j = 0; j < 12; ++j) asm volatile("" : "+v"(wx[rr][j]));
#pragma unroll
        for (int j = 0; j < 16; ++j) asm volatile("" : "+v"(wh[rr][j]));
    }

    // biases on lane c==0 only (summed once by the butterfly)
    float bR = 0.f, bZ = 0.f, bAn = 0.f, bHn = 0.f;
    if (c == 0) {
        bR  = b_ih[rg] + b_hh[rg];
        bZ  = b_ih[rg + 128] + b_hh[rg + 128];
        bAn = b_ih[rg + 256];
        bHn = b_hh[rg + 256];
    }
    asm volatile("" : "+v"(bR), "+v"(bZ), "+v"(bAn), "+v"(bHn));

    // prefetch addressing: uniform base (xb + tn) + per-thread element offset
    const float* xb = x + (size_t)b * M_ * T_;
    const int  toff = tid * T_;               // element offset for this thread's row
    const int  pc = tid / 20, pi = tid % 20;  // publish slot (tid < 80)

    if (tid < 2 * 4 * 24) ((short*)xs16)[tid] = 0;   // zero pads (one-time)
    __syncthreads();
    if (tid < M_) xs16[0][pc][pi] = (_Float16)xb[toff];   // x col t=0
    if (tid < H_) h16[0][tid] = (_Float16)0.0f;

    float h_r = 0.0f;   // master h (consistent across the quad)

    for (int t = 0; t < T_; ++t) {
        __syncthreads();                 // h16[cb] (h_{t-1}) and xs16[cb] (x_t) ready
        const int cb = t & 1, nb = cb ^ 1;

        // prefetch x column t+1: uniform pointer + vgpr offset (saddr form)
        float xv = 0.0f;
        const int tn = (t + 1 < T_) ? (t + 1) : (T_ - 1);   // scalar
        const float* xc = xb + tn;                          // scalar pointer
        if (tid < M_) xv = xc[toff];

        // operand fragment (shared by this thread's 3 rows)
        const uint4* xp = (const uint4*)(&xs16[cb][c][0]);
        uint4 xA = xp[0], xB = xp[1], xC = xp[2];
        uint32_t ox[12] = { xA.x, xA.y, xA.z, xA.w, xB.x, xB.y, xB.z, xB.w,
                            xC.x, xC.y, xC.z, xC.w };
        const uint4* hq = (const uint4*)(&h16[cb][32 * c]);
        uint4 hA = hq[0], hB = hq[1], hC = hq[2], hD = hq[3];
        uint32_t oh[16] = { hA.x, hA.y, hA.z, hA.w, hB.x, hB.y, hB.z, hB.w,
                            hC.x, hC.y, hC.z, hC.w, hD.x, hD.y, hD.z, hD.w };

        // 3 rows x 52 cols; chains interleaved (r/z/n per j) for latency hiding
        float a_r = bR, a_z = bZ, a_n = bAn, h_n = bHn;
#pragma unroll
        for (int j = 0; j < 12; ++j) {
            a_r = dot2f(wx[0][j], ox[j], a_r);
            a_z = dot2f(wx[1][j], ox[j], a_z);
            a_n = dot2f(wx[2][j], ox[j], a_n);
        }
#pragma unroll
        for (int j = 0; j < 16; ++j) {
            a_r = dot2f(wh[0][j], oh[j], a_r);
            a_z = dot2f(wh[1][j], oh[j], a_z);
            h_n = dot2f(wh[2][j], oh[j], h_n);
        }

        a_r = qsum(a_r); a_z = qsum(a_z);
        a_n = qsum(a_n); h_n = qsum(h_n);

        // publish prefetched x column into the other buffer (disjoint from reads)
        if (tid < M_) xs16[nb][pc][pi] = (_Float16)xv;

        // ---- gates inline (all 4 lanes of the quad, redundantly) ----
        const float r  = fast_sigmoid(a_r);
        const float z  = fast_sigmoid(a_z);
        const float nv = fast_tanh(fmaf(r, h_n, a_n));
        h_r = fmaf(z, h_r - nv, nv);            // (1-z)*n + z*h
        if (c == 0) h16[nb][rg] = (_Float16)h_r;
    }

    if (c == 0) out[(size_t)b * H_ + rg] = h_r;
}

extern "C" void kernel_launch(void* const* d_in, const int* in_sizes, int n_in,
                              void* d_out, int out_size, void* d_ws, size_t ws_size,
                              hipStream_t stream) {
    const float* x    = (const float*)d_in[0];
    const float* W_ih = (const float*)d_in[1];
    const float* W_hh = (const float*)d_in[2];
    const float* b_ih = (const float*)d_in[3];
    const float* b_hh = (const float*)d_in[4];
    float* out = (float*)d_out;

    gru_kernel<<<dim3(B_), dim3(512), 0, stream>>>(x, W_ih, W_hh, b_ih, b_hh, out);
}

// Round 7
// 656.037 us; speedup vs baseline: 2.1712x; 1.1371x over previous
//
#include <hip/hip_runtime.h>
#include <stdint.h>

#define B_  256
#define M_  80
#define T_  1000
#define H_  128
#define KX  96    // x-side K padded 80 -> 96

typedef _Float16 half8 __attribute__((ext_vector_type(8)));
typedef float    f32x4 __attribute__((ext_vector_type(4)));

#define LOG2E 1.44269504f

__device__ __forceinline__ float fast_sigmoid(float v) {
    return __builtin_amdgcn_rcpf(1.0f + __builtin_amdgcn_exp2f(-LOG2E * v));
}
__device__ __forceinline__ float fast_tanh(float v) {
    return fmaf(-2.0f, __builtin_amdgcn_rcpf(1.0f + __builtin_amdgcn_exp2f(2.0f * LOG2E * v)), 1.0f);
}

// combined K axis: k in [0,128) -> h-side (W_hh), k in [128,224) -> x-side (W_ih; >=80 pad 0)
__device__ __forceinline__ float wget(const float* __restrict__ W_ih,
                                      const float* __restrict__ W_hh,
                                      int row, int k) {
    if (k < H_) return W_hh[row * H_ + k];
    const int c = k - H_;
    return (c < M_) ? W_ih[row * M_ + c] : 0.0f;
}

#define MFMA(A, Bf, C) __builtin_amdgcn_mfma_f32_16x16x32_f16((A), (Bf), (C), 0, 0, 0)

// One block per batch element (grid 256 = CU count), 512 threads = 8 waves
// (2/SIMD). Wave w owns hidden tile [16w,16w+16): computes all 3 gates via
// MFMA 16x16x32 f16. The single batch row is BROADCAST to all 16 M-rows
// (every lane reads the same k-slice from LDS) so all D rows are identical
// -> gates computed redundantly per lane on acc[0], lanes 0..15 publish.
// Verified layouts: A[m=lane&15][k=(lane>>4)*8+j], B[k=(lane>>4)*8+j][n=lane&15],
// D[row=(lane>>4)*4+reg][col=lane&15]. One barrier/step; h & x double-buffered.
__global__ __launch_bounds__(512, 2) void gru_kernel(
    const float* __restrict__ x,      // (B, M, T)
    const float* __restrict__ W_ih,   // (3H, M)
    const float* __restrict__ W_hh,   // (3H, H)
    const float* __restrict__ b_ih,   // (3H,)
    const float* __restrict__ b_hh,   // (3H,)
    float* __restrict__ out)          // (B, H)
{
    const int b   = blockIdx.x;
    const int tid = threadIdx.x;
    const int l   = tid & 63;
    const int w   = tid >> 6;     // wave id 0..7
    const int jn  = l & 15;       // n (column) within tile
    const int kq  = l >> 4;       // quad id: k-base = 8*kq
    const int hid = w * 16 + jn;  // hidden unit this lane's column maps to

    __shared__ __align__(16) _Float16 h16[2][H_];   // h state, f16, double-buffered
    __shared__ __align__(16) _Float16 xs[2][KX];    // x column, f16, double-buffered

    // ---- one-time: pack weight B-fragments (f16) into registers ----
    half8 wr[7], wz[7], wnh[4], wnx[3];
#pragma unroll
    for (int f = 0; f < 7; ++f)
#pragma unroll
        for (int j = 0; j < 8; ++j) {
            const int k = 32 * f + kq * 8 + j;
            wr[f][j] = (_Float16)wget(W_ih, W_hh, hid,       k);
            wz[f][j] = (_Float16)wget(W_ih, W_hh, H_ + hid,  k);
        }
#pragma unroll
    for (int f = 0; f < 4; ++f)
#pragma unroll
        for (int j = 0; j < 8; ++j)
            wnh[f][j] = (_Float16)wget(W_ih, W_hh, 2 * H_ + hid, 32 * f + kq * 8 + j);
#pragma unroll
    for (int f = 0; f < 3; ++f)
#pragma unroll
        for (int j = 0; j < 8; ++j)
            wnx[f][j] = (_Float16)wget(W_ih, W_hh, 2 * H_ + hid, H_ + 32 * f + kq * 8 + j);
    // pin: defeat load-sinking (R1 lesson)
#pragma unroll
    for (int f = 0; f < 7; ++f) { asm volatile("" : "+v"(wr[f])); asm volatile("" : "+v"(wz[f])); }
#pragma unroll
    for (int f = 0; f < 4; ++f) asm volatile("" : "+v"(wnh[f]));
#pragma unroll
    for (int f = 0; f < 3; ++f) asm volatile("" : "+v"(wnx[f]));

    // biases (n-gate split: x-side and h-side kept separate because n = tanh(xn + r*hn))
    const float bR  = b_ih[hid] + b_hh[hid];
    const float bZ  = b_ih[H_ + hid] + b_hh[H_ + hid];
    const float bNX = b_ih[2 * H_ + hid];
    const float bNH = b_hh[2 * H_ + hid];

    const float* xb  = x + (size_t)b * M_ * T_;
    const int    toff = tid * T_;     // used only when tid < M_

    // init LDS (same-thread overwrite, ordered by loop-top barrier)
    if (tid < H_) h16[0][tid] = (_Float16)0.0f;
    if (tid < 2 * KX) ((short*)xs)[tid] = 0;                // zero both buffers incl pads
    if (tid < M_) xs[0][tid] = (_Float16)xb[toff];          // x column t=0

    float h_r = 0.0f;   // master h (redundant but bitwise-consistent across lanes)

    for (int t = 0; t < T_; ++t) {
        __syncthreads();               // h16[cb] (h_{t-1}) and xs[cb] (x_t) ready
        const int cb = t & 1, nb = cb ^ 1;

        // prefetch x column t+1 (uniform base + vgpr offset)
        float xv = 0.0f;
        const int tn = (t + 1 < T_) ? (t + 1) : (T_ - 1);
        const float* xc = xb + tn;
        if (tid < M_) xv = xc[toff];

        // ---- A-fragments: broadcast the single batch row to all 16 M-rows ----
        const int ko = kq * 8;
        const half8 ah0 = *(const half8*)&h16[cb][ko];
        const half8 ah1 = *(const half8*)&h16[cb][32 + ko];
        const half8 ah2 = *(const half8*)&h16[cb][64 + ko];
        const half8 ah3 = *(const half8*)&h16[cb][96 + ko];
        const half8 ax0 = *(const half8*)&xs[cb][ko];
        const half8 ax1 = *(const half8*)&xs[cb][32 + ko];
        const half8 ax2 = *(const half8*)&xs[cb][64 + ko];

        f32x4 aR  = { bR,  bR,  bR,  bR  };
        f32x4 aZ  = { bZ,  bZ,  bZ,  bZ  };
        f32x4 aNX = { bNX, bNX, bNX, bNX };
        f32x4 aNH = { bNH, bNH, bNH, bNH };

        // h-side K (4 frags) — 3 chains interleaved
        aR  = MFMA(ah0, wr[0],  aR);
        aZ  = MFMA(ah0, wz[0],  aZ);
        aNH = MFMA(ah0, wnh[0], aNH);
        aR  = MFMA(ah1, wr[1],  aR);
        aZ  = MFMA(ah1, wz[1],  aZ);
        aNH = MFMA(ah1, wnh[1], aNH);
        aR  = MFMA(ah2, wr[2],  aR);
        aZ  = MFMA(ah2, wz[2],  aZ);
        aNH = MFMA(ah2, wnh[2], aNH);
        aR  = MFMA(ah3, wr[3],  aR);
        aZ  = MFMA(ah3, wz[3],  aZ);
        aNH = MFMA(ah3, wnh[3], aNH);
        // x-side K (3 frags)
        aR  = MFMA(ax0, wr[4],  aR);
        aZ  = MFMA(ax0, wz[4],  aZ);
        aNX = MFMA(ax0, wnx[0], aNX);
        aR  = MFMA(ax1, wr[5],  aR);
        aZ  = MFMA(ax1, wz[5],  aZ);
        aNX = MFMA(ax1, wnx[1], aNX);
        aR  = MFMA(ax2, wr[6],  aR);
        aZ  = MFMA(ax2, wz[6],  aZ);
        aNX = MFMA(ax2, wnx[2], aNX);

        // publish prefetched x column (nb buffer — disjoint from this step's reads)
        if (tid < M_) xs[nb][tid] = (_Float16)xv;

        // ---- gates: all D rows identical -> use acc[0]; redundant across lanes ----
        const float r  = fast_sigmoid(aR[0]);
        const float z  = fast_sigmoid(aZ[0]);
        const float nv = fast_tanh(fmaf(r, aNH[0], aNX[0]));
        h_r = fmaf(z, h_r - nv, nv);          // (1-z)*n + z*h
        if (l < 16) h16[nb][hid] = (_Float16)h_r;
    }

    if (l < 16) out[(size_t)b * H_ + hid] = h_r;
}

extern "C" void kernel_launch(void* const* d_in, const int* in_sizes, int n_in,
                              void* d_out, int out_size, void* d_ws, size_t ws_size,
                              hipStream_t stream) {
    const float* x    = (const float*)d_in[0];
    const float* W_ih = (const float*)d_in[1];
    const float* W_hh = (const float*)d_in[2];
    const float* b_ih = (const float*)d_in[3];
    const float* b_hh = (const float*)d_in[4];
    float* out = (float*)d_out;

    gru_kernel<<<dim3(B_), dim3(512), 0, stream>>>(x, W_ih, W_hh, b_ih, b_hh, out);
}